// Round 7
// baseline (371.839 us; speedup 1.0000x reference)
//
#include <hip/hip_runtime.h>
#include <hip/hip_bf16.h>
#include <hip/hip_cooperative_groups.h>

namespace cg = cooperative_groups;

// Problem constants
#define N_NODES 8
#define N_EDGES 64
#define CO 64
#define OH 128
#define OW 128
#define FEAT 1024
#define BN_EPS 1e-5f

// Workspace layout (bytes):
//   pooled @ 0       : 64*64 fp32 = 16,384   (pair-code indexed, zeroed in P0)
//   wb2    @ 16384   : 24*128*8 bf16 = 49,152
//   shiftb @ 65536   : 64 fp32 = 256
//   A2     @ 65792   : 16,777,216
//   B2     @ 16843008: 16,777,216            (ends 33,620,224)
#define OFF_POOLED 0
#define OFF_WB     16384
#define OFF_SHIFT  65536
#define OFF_A      65792
#define OFF_B      (65792 + 16777216)

#define RS_W 136   // conv raw row stride in u32 words

typedef short bf16x8 __attribute__((ext_vector_type(8)));
typedef float f32x4  __attribute__((ext_vector_type(4)));

__device__ __forceinline__ unsigned short f2bf(float f) {   // RNE f32->bf16
    unsigned u = __float_as_uint(f);
    u += 0x7fffu + ((u >> 16) & 1u);
    return (unsigned short)(u >> 16);
}
__device__ __forceinline__ float blo(unsigned u) { return __uint_as_float(u << 16); }
__device__ __forceinline__ float bhi(unsigned u) { return __uint_as_float(u & 0xffff0000u); }

// ---------------------------------------------------------------------------
// Single cooperative kernel: P0 repack -> P1 conv(x4) -> P2 pool(x4) -> P3
// head, separated by grid.sync(). 256 blocks x 512 thr — grid kept at <=
// 1 block/CU so the runtime's cooperative-launch occupancy validation
// (64 KiB sharedMemPerBlock accounting, 36.9 KB LDS -> 1 blk/CU) accepts it.
// (R6 failure: 512 blocks > computed max cooperative grid -> launch error.)
__global__ __launch_bounds__(512, 4) void fused_kernel(
        const float* __restrict__ x, const int* __restrict__ ei,
        const float* __restrict__ w,
        const float* __restrict__ gamma, const float* __restrict__ beta,
        const float* __restrict__ mean,  const float* __restrict__ var,
        const float* __restrict__ fc_w,  const float* __restrict__ fc_b,
        const float* __restrict__ xyz_w, const float* __restrict__ xyz_b,
        const float* __restrict__ wpqr_w,const float* __restrict__ wpqr_b,
        float* __restrict__ out,
        float* __restrict__ pooled, unsigned short* __restrict__ wb2,
        float* __restrict__ shiftb,
        unsigned short* __restrict__ A2, unsigned short* __restrict__ B2) {
    cg::grid_group grid = cg::this_grid();
    int t   = threadIdx.x;
    int blk = blockIdx.x;

    __shared__ __align__(16) char smem[36864];

    // ---------------- P0: weight repack + BN fold + pooled zero -------------
    {
        int idx = blk * 512 + t;
        if (idx < 2 * 64 * 192) {
            int tp = idx % 192;
            int c  = (idx / 192) & 63;
            int h  = idx / (192 * 64);
            int rr = tp >> 3, kx = tp & 7;
            float val = 0.f;
            if (rr < 21 && kx < 7) {
                int ci = rr / 7, ky = rr % 7;
                float sc = gamma[c] * rsqrtf(var[c] + BN_EPS);
                val = w[((c * 6 + h * 3 + ci) * 7 + ky) * 7 + kx] * sc;
            }
            wb2[(rr * 128 + h * 64 + c) * 8 + kx] = f2bf(val);
        }
        if (idx < 64) {
            float sc = gamma[idx] * rsqrtf(var[idx] + BN_EPS);
            shiftb[idx] = beta[idx] - mean[idx] * sc;
        }
        if (idx < 64 * 64) pooled[idx] = 0.f;
    }
    __threadfence();
    grid.sync();

    // ---------------- P1: MFMA conv, 4 oy-rows per block --------------------
    {
        unsigned* rawu = (unsigned*)smem;            // [24][136] u32
        int wv = t >> 6, lane = t & 63;
        int h  = wv & 1, wg = wv >> 1;
        int quad = lane >> 4, m = lane & 15;

        for (int pass = 0; pass < 4; ++pass) {
            int cb = pass * 256 + blk;               // 0..1023
            int n  = cb >> 7, oy = cb & 127;

            const float* img = x + (size_t)n * (3 * 256 * 256);
            for (int k = t; k < 24 * RS_W; k += 512) {
                int u  = k % RS_W;
                int rr = k / RS_W;
                unsigned val = 0u;
                if (rr < 21 && u < 131) {
                    int ci = (rr * 147) >> 10;       // rr/7 for rr<24
                    int ky = rr - ci * 7;
                    int iy = 2 * oy - 3 + ky;
                    if ((unsigned)iy < 256u) {
                        int c0 = 2 * u - 3;
                        const float* row = img + (ci * 256 + iy) * 256;
                        float f0 = ((unsigned)c0 < 256u) ? row[c0] : 0.f;
                        float f1 = ((unsigned)(c0 + 1) < 256u) ? row[c0 + 1] : 0.f;
                        val = (unsigned)f2bf(f0) | ((unsigned)f2bf(f1) << 16);
                    }
                }
                rawu[k] = val;
            }
            __syncthreads();

            f32x4 acc[4][2];
#pragma unroll
            for (int ct = 0; ct < 4; ++ct) {
                acc[ct][0] = (f32x4){0.f, 0.f, 0.f, 0.f};
                acc[ct][1] = (f32x4){0.f, 0.f, 0.f, 0.f};
            }

            const bf16x8* wbv = (const bf16x8*)wb2;

#pragma unroll 2
            for (int s = 0; s < 6; ++s) {
                int rq = 4 * s + quad;
                bf16x8 afrag[2];                     // image: A[m=px][k]
#pragma unroll
                for (int nt = 0; nt < 2; ++nt) {
                    int ox = 32 * wg + 16 * nt + m;
                    int base = rq * RS_W + ox;
                    union { unsigned u[4]; bf16x8 v; } bb;
                    bb.u[0] = rawu[base];     bb.u[1] = rawu[base + 1];
                    bb.u[2] = rawu[base + 2]; bb.u[3] = rawu[base + 3];
                    afrag[nt] = bb.v;
                }
#pragma unroll
                for (int ct = 0; ct < 4; ++ct) {
                    bf16x8 wfrag = wbv[rq * 128 + h * 64 + 16 * ct + m];
#pragma unroll
                    for (int nt = 0; nt < 2; ++nt)
                        acc[ct][nt] = __builtin_amdgcn_mfma_f32_16x16x32_bf16(
                                          afrag[nt], wfrag, acc[ct][nt], 0, 0, 0);
                }
            }

            float sh[4] = {0.f, 0.f, 0.f, 0.f};
            if (h) {
#pragma unroll
                for (int ct = 0; ct < 4; ++ct) sh[ct] = shiftb[16 * ct + m];
            }

            __syncthreads();                         // smem -> transpose buffer
            unsigned short* T = (unsigned short*)smem;   // [128][136]

#pragma unroll
            for (int ct = 0; ct < 4; ++ct) {
                int chp = h * 64 + 16 * ct + m;
#pragma unroll
                for (int nt = 0; nt < 2; ++nt) {
                    int px0 = 32 * wg + 16 * nt + 4 * quad;
                    float v0 = acc[ct][nt][0] + sh[ct];
                    float v1 = acc[ct][nt][1] + sh[ct];
                    float v2 = acc[ct][nt][2] + sh[ct];
                    float v3 = acc[ct][nt][3] + sh[ct];
                    uint2 pk;
                    pk.x = (unsigned)f2bf(v0) | ((unsigned)f2bf(v1) << 16);
                    pk.y = (unsigned)f2bf(v2) | ((unsigned)f2bf(v3) << 16);
                    *(uint2*)&T[chp * 136 + px0] = pk;
                }
            }
            __syncthreads();

            int row = t >> 2, slot = t & 3;
            int hh = row >> 6, ch = row & 63;
            unsigned short* dst = (hh ? B2 : A2)
                                + ((size_t)(n * CO + ch) << 14) + (oy << 7)
                                + slot * 32;
#pragma unroll
            for (int i = 0; i < 4; ++i)
                *(uint4*)(dst + i * 8) = *(uint4*)&T[row * 136 + slot * 32 + i * 8];
            __syncthreads();                         // protect smem for next pass
        }
    }
    __threadfence();
    grid.sync();

    // ---------------- P2: pool over 36 distinct pairs, 4 (c,rt) per block ---
    {
        unsigned short* S = (unsigned short*)smem;   // [2*8][9][128]
        int wv = t >> 6, lane = t & 63;
        int esub = lane >> 4, tc = lane & 15;

        for (int pass = 0; pass < 4; ++pass) {
            int pb = pass * 256 + blk;               // 0..1023
            int c  = pb >> 4;
            int rt = pb & 15;

            __syncthreads();                         // guard smem reuse
            for (int k = t; k < 2304; k += 512) {
                int slot = k & 15;
                int r    = (k >> 4) % 9;
                int tn   = (k >> 4) / 9;
                int grow = 8 * rt - 1 + r;
                uint4 v = make_uint4(0u, 0u, 0u, 0u);
                if (grow >= 0) {
                    const unsigned short* src = (tn >= 8) ? B2 : A2;
                    int node = tn & 7;
                    v = *(const uint4*)(src + ((size_t)(node * CO + c) << 14)
                                            + (grow << 7) + slot * 8);
                }
                *(uint4*)&S[tn * 1152 + (r << 7) + slot * 8] = v;
            }
            __syncthreads();

            for (int i = 0; i < 2; ++i) {
                int slot0 = 32 * i + wv * 4;         // wave's first pair slot
                if (slot0 >= 36) continue;           // wave-uniform skip
                int sidx = slot0 + esub;
                bool valid = sidx < 36;
                int ss = valid ? sidx : 0;
                int pi = 0, rem = ss;                // unrank (pi<=pj)
                while (rem >= 8 - pi) { rem -= 8 - pi; ++pi; }
                int pj = pi + rem;
                const unsigned short* pa  = &S[pi * 1152];
                const unsigned short* pb2 = &S[(8 + pj) * 1152];

                float mx[4][4];
#pragma unroll
                for (int p = 0; p < 4; ++p)
#pragma unroll
                    for (int q = 0; q < 4; ++q) mx[p][q] = 0.f;

#pragma unroll
                for (int r = 0; r < 9; ++r) {
                    uint4 ga = *(const uint4*)(pa + (r << 7) + tc * 8);
                    uint4 gb = *(const uint4*)(pb2 + (r << 7) + tc * 8);
                    float ha = 0.f, hb = 0.f;
                    if (tc > 0) {
                        ha = bhi(*(const unsigned*)(pa + (r << 7) + tc * 8 - 2));
                        hb = bhi(*(const unsigned*)(pb2 + (r << 7) + tc * 8 - 2));
                    }
                    float z0 = ha + hb;
                    float z1 = blo(ga.x) + blo(gb.x), z2 = bhi(ga.x) + bhi(gb.x);
                    float z3 = blo(ga.y) + blo(gb.y), z4 = bhi(ga.y) + bhi(gb.y);
                    float z5 = blo(ga.z) + blo(gb.z), z6 = bhi(ga.z) + bhi(gb.z);
                    float z7 = blo(ga.w) + blo(gb.w), z8 = bhi(ga.w) + bhi(gb.w);
                    float h0 = fmaxf(fmaxf(z0, z1), z2);
                    float h1 = fmaxf(fmaxf(z2, z3), z4);
                    float h2 = fmaxf(fmaxf(z4, z5), z6);
                    float h3 = fmaxf(fmaxf(z6, z7), z8);
                    if (r & 1) {
                        int p = (r - 1) >> 1;
                        mx[p][0] = fmaxf(mx[p][0], h0); mx[p][1] = fmaxf(mx[p][1], h1);
                        mx[p][2] = fmaxf(mx[p][2], h2); mx[p][3] = fmaxf(mx[p][3], h3);
                    } else {
                        if (r >= 2) {
                            int p = (r >> 1) - 1;
                            mx[p][0] = fmaxf(mx[p][0], h0); mx[p][1] = fmaxf(mx[p][1], h1);
                            mx[p][2] = fmaxf(mx[p][2], h2); mx[p][3] = fmaxf(mx[p][3], h3);
                        }
                        if (r <= 6) {
                            int p = r >> 1;
                            mx[p][0] = fmaxf(mx[p][0], h0); mx[p][1] = fmaxf(mx[p][1], h1);
                            mx[p][2] = fmaxf(mx[p][2], h2); mx[p][3] = fmaxf(mx[p][3], h3);
                        }
                    }
                }

                float sum = 0.f;
#pragma unroll
                for (int p = 0; p < 4; ++p)
#pragma unroll
                    for (int q = 0; q < 4; ++q) sum += fmaxf(mx[p][q], 0.f);

                sum += __shfl_down(sum, 8, 64);
                sum += __shfl_down(sum, 4, 64);
                sum += __shfl_down(sum, 2, 64);
                sum += __shfl_down(sum, 1, 64);
                if (tc == 0 && valid)
                    atomicAdd(&pooled[((pi << 3) + pj) * 64 + c], sum);
            }
        }
    }
    __threadfence();
    grid.sync();

    // ---------------- P3: head (blocks 0..63, one edge each) ----------------
    if (blk < N_EDGES) {
        int e = blk;
        float* pl  = (float*)smem;          // [64]
        float* red = pl + 64;               // [8][6]
        int a0 = ei[e], a1 = ei[N_EDGES + e];
        int code = (min(a0, a1) << 3) + max(a0, a1);
        if (t < CO) pl[t] = pooled[(code << 6) + t] * (1.f / 4096.f);
        __syncthreads();

        float s[6] = {0.f, 0.f, 0.f, 0.f, 0.f, 0.f};
#pragma unroll
        for (int ff = 0; ff < 2; ++ff) {
            int f = ff * 512 + t;
            const float* wr = fc_w + f * CO;
            float d = fc_b[f];
#pragma unroll
            for (int c = 0; c < CO; ++c) d = fmaf(pl[c], wr[c], d);
            d = fmaxf(d, 0.f);
#pragma unroll
            for (int r = 0; r < 3; ++r) {
                s[r]     = fmaf(d, xyz_w[r * FEAT + f],  s[r]);
                s[3 + r] = fmaf(d, wpqr_w[r * FEAT + f], s[3 + r]);
            }
        }
#pragma unroll
        for (int r = 0; r < 6; ++r)
#pragma unroll
            for (int off = 32; off > 0; off >>= 1)
                s[r] += __shfl_down(s[r], off, 64);

        if ((t & 63) == 0) {
#pragma unroll
            for (int r = 0; r < 6; ++r) red[(t >> 6) * 6 + r] = s[r];
        }
        __syncthreads();
        if (t < 6) {
            float v = 0.f;
#pragma unroll
            for (int wv2 = 0; wv2 < 8; ++wv2) v += red[wv2 * 6 + t];
            v += (t < 3) ? xyz_b[t] : wpqr_b[t - 3];
            out[48 + e * 6 + t] = v;
            if (e < 8) out[e * 6 + t] = v;
        }
    }
}

// ---------------------------------------------------------------------------
extern "C" void kernel_launch(void* const* d_in, const int* in_sizes, int n_in,
                              void* d_out, int out_size, void* d_ws, size_t ws_size,
                              hipStream_t stream) {
    const float* x        = (const float*)d_in[0];
    const int*   ei       = (const int*)d_in[1];
    const float* conv1_w  = (const float*)d_in[2];
    const float* bn_gamma = (const float*)d_in[3];
    const float* bn_beta  = (const float*)d_in[4];
    const float* bn_mean  = (const float*)d_in[5];
    const float* bn_var   = (const float*)d_in[6];
    const float* fc_w     = (const float*)d_in[7];
    const float* fc_b     = (const float*)d_in[8];
    const float* xyz_w    = (const float*)d_in[9];
    const float* xyz_b    = (const float*)d_in[10];
    const float* wpqr_w   = (const float*)d_in[11];
    const float* wpqr_b   = (const float*)d_in[12];
    float* out = (float*)d_out;

    char* ws = (char*)d_ws;
    float*          pooled = (float*)(ws + OFF_POOLED);
    unsigned short* wb2    = (unsigned short*)(ws + OFF_WB);
    float*          shiftb = (float*)(ws + OFF_SHIFT);
    unsigned short* A2     = (unsigned short*)(ws + OFF_A);
    unsigned short* B2     = (unsigned short*)(ws + OFF_B);

    void* args[] = {
        (void*)&x, (void*)&ei, (void*)&conv1_w,
        (void*)&bn_gamma, (void*)&bn_beta, (void*)&bn_mean, (void*)&bn_var,
        (void*)&fc_w, (void*)&fc_b, (void*)&xyz_w, (void*)&xyz_b,
        (void*)&wpqr_w, (void*)&wpqr_b, (void*)&out,
        (void*)&pooled, (void*)&wb2, (void*)&shiftb, (void*)&A2, (void*)&B2
    };
    hipLaunchCooperativeKernel((const void*)fused_kernel, dim3(256), dim3(512),
                               args, 0, stream);
}

// Round 8
// 139.235 us; speedup vs baseline: 2.6706x; 2.6706x over previous
//
#include <hip/hip_runtime.h>
#include <hip/hip_bf16.h>

// Problem constants
#define N_NODES 8
#define N_EDGES 64
#define CO 64
#define OH 128
#define OW 128
#define FEAT 1024
#define BN_EPS 1e-5f

// Workspace layout (bytes):
//   partial @ 0      : 16 rt x 36 pairs x 64 c fp32 = 147,456
//                      (written unconditionally by pool -> no zero-init needed)
//   A2     @ 151552  : 8*64*128*128 bf16 = 16,777,216
//   B2     @ 16928768: 16,777,216   (ends ~33.7 MB, ws is 256 MiB)
#define OFF_PARTIAL 0
#define OFF_A       151552
#define OFF_B       (151552 + 16777216)

#define RS_W 136   // conv raw row stride in u32 words

typedef short bf16x8 __attribute__((ext_vector_type(8)));
typedef float f32x4  __attribute__((ext_vector_type(4)));

__device__ __forceinline__ unsigned short f2bf(float f) {   // RNE f32->bf16
    unsigned u = __float_as_uint(f);
    u += 0x7fffu + ((u >> 16) & 1u);
    return (unsigned short)(u >> 16);
}
__device__ __forceinline__ float blo(unsigned u) { return __uint_as_float(u << 16); }
__device__ __forceinline__ float bhi(unsigned u) { return __uint_as_float(u & 0xffff0000u); }

// ---------------------------------------------------------------------------
// K1: MFMA conv with INLINE weight repack (no separate repack kernel).
// Grid 1024, 512 thr = 8 waves (h = wv&1 half, wg = wv>>1 px-group).
// XCD-aware decode (assumes XCD = blockIdx%8 round-robin): row-group
// r16 = oy>>4 pinned to XCD r16 so pool (tile rt, r16 = rt>>1) reads the
// same XCD's L2. Epilogue transpose is XOR-swizzled -> conflict-floor.
__global__ __launch_bounds__(512, 4) void conv_kernel(
        const float* __restrict__ x, const float* __restrict__ w,
        const float* __restrict__ gamma, const float* __restrict__ beta,
        const float* __restrict__ mean,  const float* __restrict__ var,
        unsigned short* __restrict__ A2, unsigned short* __restrict__ B2) {
    int bx  = blockIdx.x;
    int r16 = bx & 7;
    int idx = bx >> 3;                 // [0,128)
    int n   = idx >> 4;
    int oy  = (r16 << 4) + (idx & 15);
    int t   = threadIdx.x;

    // smem: wlds @0 (49,152 B = [24 rr][128 chp][8 kx] bf16),
    //       rawu @49,152 ([24][136] u32 = 13,056 B).
    // Epilogue reuses @0 as T[128 chp][128 px] bf16 XOR-swizzled (32,768 B).
    __shared__ __align__(16) char smem[62208];
    uint4*    wl4  = (uint4*)smem;
    unsigned* rawu = (unsigned*)(smem + 49152);

    // inline weight repack + BN-scale fold: granule k2 = rr*128 + chp
    for (int k2 = t; k2 < 3072; k2 += 512) {
        int rr  = k2 >> 7;
        int chp = k2 & 127;
        int h   = chp >> 6, c = chp & 63;
        union { unsigned short s[8]; uint4 v; } pk;
        pk.v = make_uint4(0u, 0u, 0u, 0u);
        if (rr < 21) {
            int ci = (rr * 147) >> 10;     // rr/7 for rr<24
            int ky = rr - ci * 7;
            float sc = gamma[c] * rsqrtf(var[c] + BN_EPS);
            const float* wr = w + ((c * 6 + h * 3 + ci) * 7 + ky) * 7;
#pragma unroll
            for (int kx = 0; kx < 7; ++kx)
                pk.s[kx] = f2bf(wr[kx] * sc);
        }
        wl4[k2] = pk.v;
    }

    // stage image rows rr=(ci,ky): bf16 pairs, cols rc=2u,2u+1 <-> img col rc-3
    const float* img = x + (size_t)n * (3 * 256 * 256);
    for (int k = t; k < 24 * RS_W; k += 512) {
        int u  = k % RS_W;
        int rr = k / RS_W;
        unsigned val = 0u;
        if (rr < 21 && u < 131) {
            int ci = (rr * 147) >> 10;
            int ky = rr - ci * 7;
            int iy = 2 * oy - 3 + ky;
            if ((unsigned)iy < 256u) {
                int c0 = 2 * u - 3;
                const float* row = img + (ci * 256 + iy) * 256;
                float f0 = ((unsigned)c0 < 256u) ? row[c0] : 0.f;
                float f1 = ((unsigned)(c0 + 1) < 256u) ? row[c0 + 1] : 0.f;
                val = (unsigned)f2bf(f0) | ((unsigned)f2bf(f1) << 16);
            }
        }
        rawu[k] = val;
    }
    __syncthreads();

    int wv = t >> 6, lane = t & 63;
    int h  = wv & 1, wg = wv >> 1;
    int quad = lane >> 4, m = lane & 15;

    f32x4 acc[4][2];
#pragma unroll
    for (int ct = 0; ct < 4; ++ct) {
        acc[ct][0] = (f32x4){0.f, 0.f, 0.f, 0.f};
        acc[ct][1] = (f32x4){0.f, 0.f, 0.f, 0.f};
    }

    const bf16x8* wlv = (const bf16x8*)smem;

#pragma unroll 2
    for (int s = 0; s < 6; ++s) {
        int rq = 4 * s + quad;
        bf16x8 afrag[2];                   // image: A[m=px][k]
#pragma unroll
        for (int nt = 0; nt < 2; ++nt) {
            int ox = 32 * wg + 16 * nt + m;
            int base = rq * RS_W + ox;
            union { unsigned u[4]; bf16x8 v; } bb;
            bb.u[0] = rawu[base];     bb.u[1] = rawu[base + 1];
            bb.u[2] = rawu[base + 2]; bb.u[3] = rawu[base + 3];
            afrag[nt] = bb.v;
        }
#pragma unroll
        for (int ct = 0; ct < 4; ++ct) {
            bf16x8 wfrag = wlv[rq * 128 + h * 64 + 16 * ct + m];   // LDS b128
#pragma unroll
            for (int nt = 0; nt < 2; ++nt)
                acc[ct][nt] = __builtin_amdgcn_mfma_f32_16x16x32_bf16(
                                  afrag[nt], wfrag, acc[ct][nt], 0, 0, 0);
        }
    }

    float sh[4] = {0.f, 0.f, 0.f, 0.f};
    if (h) {
#pragma unroll
        for (int ct = 0; ct < 4; ++ct) {
            int c = 16 * ct + m;
            float sc = gamma[c] * rsqrtf(var[c] + BN_EPS);
            sh[ct] = beta[c] - mean[c] * sc;
        }
    }

    __syncthreads();                       // smem reuse: T transpose buffer
    unsigned short* T = (unsigned short*)smem;   // [128 chp][128 px], swizzled

#pragma unroll
    for (int ct = 0; ct < 4; ++ct) {
        int chp = h * 64 + 16 * ct + m;
        int sw  = (chp & 7) << 2;          // XOR swizzle key (granule = 4 shorts)
#pragma unroll
        for (int nt = 0; nt < 2; ++nt) {
            int px0 = 32 * wg + 16 * nt + 4 * quad;
            float v0 = acc[ct][nt][0] + sh[ct];
            float v1 = acc[ct][nt][1] + sh[ct];
            float v2 = acc[ct][nt][2] + sh[ct];
            float v3 = acc[ct][nt][3] + sh[ct];
            uint2 pk;
            pk.x = (unsigned)f2bf(v0) | ((unsigned)f2bf(v1) << 16);
            pk.y = (unsigned)f2bf(v2) | ((unsigned)f2bf(v3) << 16);
            int gs = ((px0 >> 2) ^ sw);
            *(uint2*)&T[chp * 128 + gs * 4] = pk;
        }
    }
    __syncthreads();

    // cooperative coalesced store: thread -> (ch-row, 32-px slot), 4x uint4
    int row = t >> 2, slot = t & 3;
    int hh = row >> 6, ch = row & 63;
    int swr = (row & 7) << 2;
    unsigned short* dst = (hh ? B2 : A2)
                        + ((size_t)(n * CO + ch) << 14) + (oy << 7) + slot * 32;
#pragma unroll
    for (int i = 0; i < 4; ++i) {
        int g  = slot * 8 + i * 2;         // granule of px slot*32 + i*8
        int gs = g ^ swr;
        *(uint4*)(dst + i * 8) = *(uint4*)&T[row * 128 + gs * 4];
    }
}

// ---------------------------------------------------------------------------
// K2: pool over 36 distinct pairs -> non-atomic partial[rt][pair][c].
// Grid 1024 = 64 ch x 16 rt, XCD-swizzled so rt>>1 == blockIdx%8 matches the
// conv blocks that wrote rows 8rt..8rt+7 (L2-local reads).
__global__ __launch_bounds__(256, 4) void pool_kernel(
        const unsigned short* __restrict__ A2,
        const unsigned short* __restrict__ B2,
        float* __restrict__ partial) {
    int pb  = blockIdx.x;
    int xcd = pb & 7;
    int q   = pb >> 3;                 // [0,128)
    int c   = q >> 1;
    int rt  = xcd * 2 + (q & 1);
    int t   = threadIdx.x;

    __shared__ unsigned short S[2 * 8 * 9 * 128];   // plane 1152, row 128

    for (int k = t; k < 2304; k += 256) {
        int slot = k & 15;
        int r    = (k >> 4) % 9;
        int tn   = (k >> 4) / 9;
        int grow = 8 * rt - 1 + r;
        uint4 v = make_uint4(0u, 0u, 0u, 0u);
        if (grow >= 0) {
            const unsigned short* src = (tn >= 8) ? B2 : A2;
            int node = tn & 7;
            v = *(const uint4*)(src + ((size_t)(node * CO + c) << 14)
                                    + (grow << 7) + slot * 8);
        }
        *(uint4*)&S[tn * 1152 + (r << 7) + slot * 8] = v;
    }
    __syncthreads();

    int wv = t >> 6, lane = t & 63;
    int esub = lane >> 4, tc = lane & 15;

    for (int i = 0; i < 3; ++i) {
        int sidx = 12 * wv + 4 * i + esub;          // pair slot 0..47
        bool valid = sidx < 36;
        int ss = valid ? sidx : 0;
        int pi = 0, rem = ss;                        // unrank (pi<=pj)
        while (rem >= 8 - pi) { rem -= 8 - pi; ++pi; }
        int pj = pi + rem;
        const unsigned short* pa  = &S[pi * 1152];
        const unsigned short* pb2 = &S[(8 + pj) * 1152];

        float mx[4][4];
#pragma unroll
        for (int p = 0; p < 4; ++p)
#pragma unroll
            for (int qq = 0; qq < 4; ++qq) mx[p][qq] = 0.f;

#pragma unroll
        for (int r = 0; r < 9; ++r) {
            uint4 ga = *(const uint4*)(pa + (r << 7) + tc * 8);
            uint4 gb = *(const uint4*)(pb2 + (r << 7) + tc * 8);
            float ha = 0.f, hb = 0.f;
            if (tc > 0) {
                ha = bhi(*(const unsigned*)(pa + (r << 7) + tc * 8 - 2));
                hb = bhi(*(const unsigned*)(pb2 + (r << 7) + tc * 8 - 2));
            }
            float z0 = ha + hb;
            float z1 = blo(ga.x) + blo(gb.x), z2 = bhi(ga.x) + bhi(gb.x);
            float z3 = blo(ga.y) + blo(gb.y), z4 = bhi(ga.y) + bhi(gb.y);
            float z5 = blo(ga.z) + blo(gb.z), z6 = bhi(ga.z) + bhi(gb.z);
            float z7 = blo(ga.w) + blo(gb.w), z8 = bhi(ga.w) + bhi(gb.w);
            float h0 = fmaxf(fmaxf(z0, z1), z2);
            float h1 = fmaxf(fmaxf(z2, z3), z4);
            float h2 = fmaxf(fmaxf(z4, z5), z6);
            float h3 = fmaxf(fmaxf(z6, z7), z8);
            if (r & 1) {
                int p = (r - 1) >> 1;
                mx[p][0] = fmaxf(mx[p][0], h0); mx[p][1] = fmaxf(mx[p][1], h1);
                mx[p][2] = fmaxf(mx[p][2], h2); mx[p][3] = fmaxf(mx[p][3], h3);
            } else {
                if (r >= 2) {
                    int p = (r >> 1) - 1;
                    mx[p][0] = fmaxf(mx[p][0], h0); mx[p][1] = fmaxf(mx[p][1], h1);
                    mx[p][2] = fmaxf(mx[p][2], h2); mx[p][3] = fmaxf(mx[p][3], h3);
                }
                if (r <= 6) {
                    int p = r >> 1;
                    mx[p][0] = fmaxf(mx[p][0], h0); mx[p][1] = fmaxf(mx[p][1], h1);
                    mx[p][2] = fmaxf(mx[p][2], h2); mx[p][3] = fmaxf(mx[p][3], h3);
                }
            }
        }

        float sum = 0.f;
#pragma unroll
        for (int p = 0; p < 4; ++p)
#pragma unroll
            for (int qq = 0; qq < 4; ++qq) sum += fmaxf(mx[p][qq], 0.f);

        sum += __shfl_down(sum, 8, 64);
        sum += __shfl_down(sum, 4, 64);
        sum += __shfl_down(sum, 2, 64);
        sum += __shfl_down(sum, 1, 64);
        if (tc == 0 && valid)
            partial[(rt * 36 + sidx) * 64 + c] = sum;
    }
}

// ---------------------------------------------------------------------------
// K3: head — sum partial over 16 rt at pair rank, fc+relu+two heads fused.
__global__ __launch_bounds__(256) void head_kernel(
        const int* __restrict__ ei, const float* __restrict__ partial,
        const float* __restrict__ fc_w,   const float* __restrict__ fc_b,
        const float* __restrict__ xyz_w,  const float* __restrict__ xyz_b,
        const float* __restrict__ wpqr_w, const float* __restrict__ wpqr_b,
        float* __restrict__ out) {
    int e = blockIdx.x;
    int t = threadIdx.x;
    int a0 = ei[e], a1 = ei[N_EDGES + e];
    int pi = min(a0, a1), pj = max(a0, a1);
    int rank = pi * 8 - ((pi * (pi + 1)) >> 1) + pj;   // pair rank (pi<=pj)
    __shared__ float pl[CO];
    if (t < CO) {
        float s = 0.f;
#pragma unroll
        for (int rt = 0; rt < 16; ++rt)
            s += partial[(rt * 36 + rank) * 64 + t];
        pl[t] = s * (1.f / 4096.f);
    }
    __syncthreads();

    float s[6] = {0.f, 0.f, 0.f, 0.f, 0.f, 0.f};
#pragma unroll
    for (int ff = 0; ff < 4; ++ff) {
        int f = ff * 256 + t;
        const float* wr = fc_w + f * CO;
        float d = fc_b[f];
#pragma unroll
        for (int c = 0; c < CO; ++c) d = fmaf(pl[c], wr[c], d);
        d = fmaxf(d, 0.f);
#pragma unroll
        for (int r = 0; r < 3; ++r) {
            s[r]     = fmaf(d, xyz_w[r * FEAT + f],  s[r]);
            s[3 + r] = fmaf(d, wpqr_w[r * FEAT + f], s[3 + r]);
        }
    }
#pragma unroll
    for (int r = 0; r < 6; ++r)
#pragma unroll
        for (int off = 32; off > 0; off >>= 1)
            s[r] += __shfl_down(s[r], off, 64);

    __shared__ float red[4][6];
    if ((t & 63) == 0) {
#pragma unroll
        for (int r = 0; r < 6; ++r) red[t >> 6][r] = s[r];
    }
    __syncthreads();
    if (t < 6) {
        float v = red[0][t] + red[1][t] + red[2][t] + red[3][t];
        v += (t < 3) ? xyz_b[t] : wpqr_b[t - 3];
        out[48 + e * 6 + t] = v;
        if (e < 8) out[e * 6 + t] = v;
    }
}

// ---------------------------------------------------------------------------
extern "C" void kernel_launch(void* const* d_in, const int* in_sizes, int n_in,
                              void* d_out, int out_size, void* d_ws, size_t ws_size,
                              hipStream_t stream) {
    const float* x        = (const float*)d_in[0];
    const int*   ei       = (const int*)d_in[1];
    const float* conv1_w  = (const float*)d_in[2];
    const float* bn_gamma = (const float*)d_in[3];
    const float* bn_beta  = (const float*)d_in[4];
    const float* bn_mean  = (const float*)d_in[5];
    const float* bn_var   = (const float*)d_in[6];
    const float* fc_w     = (const float*)d_in[7];
    const float* fc_b     = (const float*)d_in[8];
    const float* xyz_w    = (const float*)d_in[9];
    const float* xyz_b    = (const float*)d_in[10];
    const float* wpqr_w   = (const float*)d_in[11];
    const float* wpqr_b   = (const float*)d_in[12];
    float* out = (float*)d_out;

    char* ws = (char*)d_ws;
    float*          partial = (float*)(ws + OFF_PARTIAL);
    unsigned short* A2      = (unsigned short*)(ws + OFF_A);
    unsigned short* B2      = (unsigned short*)(ws + OFF_B);

    conv_kernel<<<1024, 512, 0, stream>>>(x, conv1_w, bn_gamma, bn_beta,
                                          bn_mean, bn_var, A2, B2);
    pool_kernel<<<1024, 256, 0, stream>>>(A2, B2, partial);
    head_kernel<<<64, 256, 0, stream>>>(ei, partial, fc_w, fc_b,
                                        xyz_w, xyz_b, wpqr_w, wpqr_b, out);
}

// Round 9
// 135.293 us; speedup vs baseline: 2.7484x; 1.0291x over previous
//
#include <hip/hip_runtime.h>
#include <hip/hip_bf16.h>

// Problem constants
#define N_NODES 8
#define N_EDGES 64
#define CO 64
#define OH 128
#define OW 128
#define FEAT 1024
#define BN_EPS 1e-5f

// Workspace layout (bytes):
//   partial @ 0        : 16 rt x 36 pairs x 64 c fp32 = 147,456 (pad 151,552)
//   xpad    @ 151552   : 8*3*262*264 bf16 = 3,320,064  (padded bf16 image,
//                        3 zero rows top / cols 0-2 & 259-263 zero)
//   wb2     @ 3471616  : 24*128*8 bf16 = 49,152  ([rr][h*64+c][kx] layout)
//   A2      @ 3520768  : 16,777,216
//   B2      @ 20297984 : 16,777,216   (ends ~37.1 MB, ws is 256 MiB)
#define OFF_PARTIAL 0
#define OFF_XPAD    151552
#define OFF_WB      3471616
#define OFF_A       3520768
#define OFF_B       20297984

#define RS_W 136        // conv raw row stride in u32 words (8 mod 32 -> 2-way free)
#define XROW 132        // xpad row stride in u32 words (264 bf16)

typedef short bf16x8 __attribute__((ext_vector_type(8)));
typedef float f32x4  __attribute__((ext_vector_type(4)));

__device__ __forceinline__ unsigned short f2bf(float f) {   // RNE f32->bf16
    unsigned u = __float_as_uint(f);
    u += 0x7fffu + ((u >> 16) & 1u);
    return (unsigned short)(u >> 16);
}
__device__ __forceinline__ float blo(unsigned u) { return __uint_as_float(u << 16); }
__device__ __forceinline__ float bhi(unsigned u) { return __uint_as_float(u & 0xffff0000u); }

// ---------------------------------------------------------------------------
// K0: prep — (a) pad+convert image to bf16 once (kills all per-block cvt and
// bounds logic in conv; halo re-reads across oy-blocks become cheap u32
// copies), (b) weight repack + BN-scale fold into wb2.
// Image total: 8*3*262*132 u32 = 830,016 threads-worth.
__global__ __launch_bounds__(256) void prep_kernel(
        const float* __restrict__ x, const float* __restrict__ w,
        const float* __restrict__ gamma, const float* __restrict__ var,
        unsigned* __restrict__ xpad, unsigned short* __restrict__ wb2) {
    int idx = blockIdx.x * 256 + threadIdx.x;
    if (idx < 8 * 3 * 262 * XROW) {
        int u   = idx % XROW;            // u32 col (bf16 pair)
        int r   = idx / XROW;
        int iyp = r % 262;               // padded row
        int nc  = r / 262;               // n*3 + ci
        int iy  = iyp - 3;
        unsigned val = 0u;
        if ((unsigned)iy < 256u) {
            int c0 = 2 * u - 3;          // img col of low half
            const float* row = x + (size_t)nc * 65536 + iy * 256;
            float f0 = ((unsigned)c0 < 256u) ? row[c0] : 0.f;
            float f1 = ((unsigned)(c0 + 1) < 256u) ? row[c0 + 1] : 0.f;
            val = (unsigned)f2bf(f0) | ((unsigned)f2bf(f1) << 16);
        }
        xpad[idx] = val;
    }
    if (idx < 2 * 64 * 192) {            // weight repack (R5 layout)
        int tp = idx % 192;
        int c  = (idx / 192) & 63;
        int h  = idx / (192 * 64);
        int rr = tp >> 3, kx = tp & 7;
        float val = 0.f;
        if (rr < 21 && kx < 7) {
            int ci = rr / 7, ky = rr % 7;
            float sc = gamma[c] * rsqrtf(var[c] + BN_EPS);
            val = w[((c * 6 + h * 3 + ci) * 7 + ky) * 7 + kx] * sc;
        }
        wb2[(rr * 128 + h * 64 + c) * 8 + kx] = f2bf(val);
    }
}

// ---------------------------------------------------------------------------
// K1: MFMA conv. Grid 1024 = 8 nodes x 128 oy; 512 thr = 8 waves
// (h = wv&1, px-group wg = wv>>1). Staging is now pure aligned uint4 copies
// from xpad (no cvt, no bounds: padded row index 2oy+ky is always in range).
// Weights: global bf16x8 fragments from wb2 (L1-hot). Epilogue: XOR-swizzled
// LDS transpose -> fully coalesced uint4 stores.
__global__ __launch_bounds__(512, 4) void conv_kernel(
        const unsigned* __restrict__ xpad, const unsigned short* __restrict__ wb2,
        const float* __restrict__ gamma, const float* __restrict__ beta,
        const float* __restrict__ mean,  const float* __restrict__ var,
        unsigned short* __restrict__ A2, unsigned short* __restrict__ B2) {
    int bx  = blockIdx.x;
    int r16 = bx & 7;                  // XCD-pinned row-group (matches pool)
    int idx = bx >> 3;
    int n   = idx >> 4;
    int oy  = (r16 << 4) + (idx & 15);
    int t   = threadIdx.x;

    // one 32.8 KB buffer: rawu [24][136] u32 (13 KB) re-used as T [128][128] bf16
    __shared__ __align__(16) char smem[32768];
    unsigned* rawu = (unsigned*)smem;

    // stage: 24 rows x 34 uint4 granules (rows 21-23 and granule 33 zeroed)
    const unsigned* src = xpad + (size_t)n * (3 * 262 * XROW);
    for (int k = t; k < 24 * 34; k += 512) {
        int g  = k % 34;
        int rr = k / 34;
        uint4 v = make_uint4(0u, 0u, 0u, 0u);
        if (rr < 21 && g < 33) {
            int ci = (rr * 147) >> 10;     // rr/7 for rr<24
            int ky = rr - ci * 7;
            v = *(const uint4*)(src + (ci * 262 + 2 * oy + ky) * XROW + 4 * g);
        }
        *(uint4*)&rawu[rr * RS_W + 4 * g] = v;
    }
    __syncthreads();

    int wv = t >> 6, lane = t & 63;
    int h  = wv & 1, wg = wv >> 1;
    int quad = lane >> 4, m = lane & 15;

    f32x4 acc[4][2];
#pragma unroll
    for (int ct = 0; ct < 4; ++ct) {
        acc[ct][0] = (f32x4){0.f, 0.f, 0.f, 0.f};
        acc[ct][1] = (f32x4){0.f, 0.f, 0.f, 0.f};
    }

    const bf16x8* wbv = (const bf16x8*)wb2;

#pragma unroll 2
    for (int s = 0; s < 6; ++s) {
        int rq = 4 * s + quad;
        bf16x8 afrag[2];                   // image: A[m=px][k]
#pragma unroll
        for (int nt = 0; nt < 2; ++nt) {
            int ox = 32 * wg + 16 * nt + m;
            int base = rq * RS_W + ox;
            union { unsigned u[4]; bf16x8 v; } bb;
            bb.u[0] = rawu[base];     bb.u[1] = rawu[base + 1];
            bb.u[2] = rawu[base + 2]; bb.u[3] = rawu[base + 3];
            afrag[nt] = bb.v;
        }
#pragma unroll
        for (int ct = 0; ct < 4; ++ct) {
            bf16x8 wfrag = wbv[rq * 128 + h * 64 + 16 * ct + m];  // global, L1-hot
#pragma unroll
            for (int nt = 0; nt < 2; ++nt)
                acc[ct][nt] = __builtin_amdgcn_mfma_f32_16x16x32_bf16(
                                  afrag[nt], wfrag, acc[ct][nt], 0, 0, 0);
        }
    }

    float sh[4] = {0.f, 0.f, 0.f, 0.f};
    if (h) {
#pragma unroll
        for (int ct = 0; ct < 4; ++ct) {
            int c = 16 * ct + m;
            float sc = gamma[c] * rsqrtf(var[c] + BN_EPS);
            sh[ct] = beta[c] - mean[c] * sc;
        }
    }

    __syncthreads();                       // smem reuse: T transpose buffer
    unsigned short* T = (unsigned short*)smem;   // [128 chp][128 px], swizzled

#pragma unroll
    for (int ct = 0; ct < 4; ++ct) {
        int chp = h * 64 + 16 * ct + m;
        int sw  = (chp & 7) << 2;          // XOR swizzle key (granule = 4 shorts)
#pragma unroll
        for (int nt = 0; nt < 2; ++nt) {
            int px0 = 32 * wg + 16 * nt + 4 * quad;
            float v0 = acc[ct][nt][0] + sh[ct];
            float v1 = acc[ct][nt][1] + sh[ct];
            float v2 = acc[ct][nt][2] + sh[ct];
            float v3 = acc[ct][nt][3] + sh[ct];
            uint2 pk;
            pk.x = (unsigned)f2bf(v0) | ((unsigned)f2bf(v1) << 16);
            pk.y = (unsigned)f2bf(v2) | ((unsigned)f2bf(v3) << 16);
            int gs = ((px0 >> 2) ^ sw);
            *(uint2*)&T[chp * 128 + gs * 4] = pk;
        }
    }
    __syncthreads();

    int row = t >> 2, slot = t & 3;
    int hh = row >> 6, ch = row & 63;
    int swr = (row & 7) << 2;
    unsigned short* dst = (hh ? B2 : A2)
                        + ((size_t)(n * CO + ch) << 14) + (oy << 7) + slot * 32;
#pragma unroll
    for (int i = 0; i < 4; ++i) {
        int g  = slot * 8 + i * 2;
        int gs = g ^ swr;
        *(uint4*)(dst + i * 8) = *(uint4*)&T[row * 128 + gs * 4];
    }
}

// ---------------------------------------------------------------------------
// K2: pool over 36 distinct pairs -> non-atomic partial[rt][pair][c].
// Grid 1024 = 64 ch x 16 rt, XCD-swizzled (rt>>1 == blockIdx%8 matches conv).
__global__ __launch_bounds__(256, 4) void pool_kernel(
        const unsigned short* __restrict__ A2,
        const unsigned short* __restrict__ B2,
        float* __restrict__ partial) {
    int pb  = blockIdx.x;
    int xcd = pb & 7;
    int q   = pb >> 3;
    int c   = q >> 1;
    int rt  = xcd * 2 + (q & 1);
    int t   = threadIdx.x;

    __shared__ unsigned short S[2 * 8 * 9 * 128];   // plane 1152, row 128

    for (int k = t; k < 2304; k += 256) {
        int slot = k & 15;
        int r    = (k >> 4) % 9;
        int tn   = (k >> 4) / 9;
        int grow = 8 * rt - 1 + r;
        uint4 v = make_uint4(0u, 0u, 0u, 0u);
        if (grow >= 0) {
            const unsigned short* src = (tn >= 8) ? B2 : A2;
            int node = tn & 7;
            v = *(const uint4*)(src + ((size_t)(node * CO + c) << 14)
                                    + (grow << 7) + slot * 8);
        }
        *(uint4*)&S[tn * 1152 + (r << 7) + slot * 8] = v;
    }
    __syncthreads();

    int wv = t >> 6, lane = t & 63;
    int esub = lane >> 4, tc = lane & 15;

    for (int i = 0; i < 3; ++i) {
        int sidx = 12 * wv + 4 * i + esub;          // pair slot 0..47
        bool valid = sidx < 36;
        int ss = valid ? sidx : 0;
        int pi = 0, rem = ss;                        // unrank (pi<=pj)
        while (rem >= 8 - pi) { rem -= 8 - pi; ++pi; }
        int pj = pi + rem;
        const unsigned short* pa  = &S[pi * 1152];
        const unsigned short* pb2 = &S[(8 + pj) * 1152];

        float mx[4][4];
#pragma unroll
        for (int p = 0; p < 4; ++p)
#pragma unroll
            for (int qq = 0; qq < 4; ++qq) mx[p][qq] = 0.f;

#pragma unroll
        for (int r = 0; r < 9; ++r) {
            uint4 ga = *(const uint4*)(pa + (r << 7) + tc * 8);
            uint4 gb = *(const uint4*)(pb2 + (r << 7) + tc * 8);
            float ha = 0.f, hb = 0.f;
            if (tc > 0) {
                ha = bhi(*(const unsigned*)(pa + (r << 7) + tc * 8 - 2));
                hb = bhi(*(const unsigned*)(pb2 + (r << 7) + tc * 8 - 2));
            }
            float z0 = ha + hb;
            float z1 = blo(ga.x) + blo(gb.x), z2 = bhi(ga.x) + bhi(gb.x);
            float z3 = blo(ga.y) + blo(gb.y), z4 = bhi(ga.y) + bhi(gb.y);
            float z5 = blo(ga.z) + blo(gb.z), z6 = bhi(ga.z) + bhi(gb.z);
            float z7 = blo(ga.w) + blo(gb.w), z8 = bhi(ga.w) + bhi(gb.w);
            float h0 = fmaxf(fmaxf(z0, z1), z2);
            float h1 = fmaxf(fmaxf(z2, z3), z4);
            float h2 = fmaxf(fmaxf(z4, z5), z6);
            float h3 = fmaxf(fmaxf(z6, z7), z8);
            if (r & 1) {
                int p = (r - 1) >> 1;
                mx[p][0] = fmaxf(mx[p][0], h0); mx[p][1] = fmaxf(mx[p][1], h1);
                mx[p][2] = fmaxf(mx[p][2], h2); mx[p][3] = fmaxf(mx[p][3], h3);
            } else {
                if (r >= 2) {
                    int p = (r >> 1) - 1;
                    mx[p][0] = fmaxf(mx[p][0], h0); mx[p][1] = fmaxf(mx[p][1], h1);
                    mx[p][2] = fmaxf(mx[p][2], h2); mx[p][3] = fmaxf(mx[p][3], h3);
                }
                if (r <= 6) {
                    int p = r >> 1;
                    mx[p][0] = fmaxf(mx[p][0], h0); mx[p][1] = fmaxf(mx[p][1], h1);
                    mx[p][2] = fmaxf(mx[p][2], h2); mx[p][3] = fmaxf(mx[p][3], h3);
                }
            }
        }

        float sum = 0.f;
#pragma unroll
        for (int p = 0; p < 4; ++p)
#pragma unroll
            for (int qq = 0; qq < 4; ++qq) sum += fmaxf(mx[p][qq], 0.f);

        sum += __shfl_down(sum, 8, 64);
        sum += __shfl_down(sum, 4, 64);
        sum += __shfl_down(sum, 2, 64);
        sum += __shfl_down(sum, 1, 64);
        if (tc == 0 && valid)
            partial[(rt * 36 + sidx) * 64 + c] = sum;
    }
}

// ---------------------------------------------------------------------------
// K3: head — sum partial over 16 rt at pair rank, fc+relu+two heads fused.
__global__ __launch_bounds__(256) void head_kernel(
        const int* __restrict__ ei, const float* __restrict__ partial,
        const float* __restrict__ fc_w,   const float* __restrict__ fc_b,
        const float* __restrict__ xyz_w,  const float* __restrict__ xyz_b,
        const float* __restrict__ wpqr_w, const float* __restrict__ wpqr_b,
        float* __restrict__ out) {
    int e = blockIdx.x;
    int t = threadIdx.x;
    int a0 = ei[e], a1 = ei[N_EDGES + e];
    int pi = min(a0, a1), pj = max(a0, a1);
    int rank = pi * 8 - ((pi * (pi + 1)) >> 1) + pj;   // pair rank (pi<=pj)
    __shared__ float pl[CO];
    if (t < CO) {
        float s = 0.f;
#pragma unroll
        for (int rt = 0; rt < 16; ++rt)
            s += partial[(rt * 36 + rank) * 64 + t];
        pl[t] = s * (1.f / 4096.f);
    }
    __syncthreads();

    float s[6] = {0.f, 0.f, 0.f, 0.f, 0.f, 0.f};
#pragma unroll
    for (int ff = 0; ff < 4; ++ff) {
        int f = ff * 256 + t;
        const float* wr = fc_w + f * CO;
        float d = fc_b[f];
#pragma unroll
        for (int c = 0; c < CO; ++c) d = fmaf(pl[c], wr[c], d);
        d = fmaxf(d, 0.f);
#pragma unroll
        for (int r = 0; r < 3; ++r) {
            s[r]     = fmaf(d, xyz_w[r * FEAT + f],  s[r]);
            s[3 + r] = fmaf(d, wpqr_w[r * FEAT + f], s[3 + r]);
        }
    }
#pragma unroll
    for (int r = 0; r < 6; ++r)
#pragma unroll
        for (int off = 32; off > 0; off >>= 1)
            s[r] += __shfl_down(s[r], off, 64);

    __shared__ float red[4][6];
    if ((t & 63) == 0) {
#pragma unroll
        for (int r = 0; r < 6; ++r) red[t >> 6][r] = s[r];
    }
    __syncthreads();
    if (t < 6) {
        float v = red[0][t] + red[1][t] + red[2][t] + red[3][t];
        v += (t < 3) ? xyz_b[t] : wpqr_b[t - 3];
        out[48 + e * 6 + t] = v;
        if (e < 8) out[e * 6 + t] = v;
    }
}

// ---------------------------------------------------------------------------
extern "C" void kernel_launch(void* const* d_in, const int* in_sizes, int n_in,
                              void* d_out, int out_size, void* d_ws, size_t ws_size,
                              hipStream_t stream) {
    const float* x        = (const float*)d_in[0];
    const int*   ei       = (const int*)d_in[1];
    const float* conv1_w  = (const float*)d_in[2];
    const float* bn_gamma = (const float*)d_in[3];
    const float* bn_beta  = (const float*)d_in[4];
    const float* bn_mean  = (const float*)d_in[5];
    const float* bn_var   = (const float*)d_in[6];
    const float* fc_w     = (const float*)d_in[7];
    const float* fc_b     = (const float*)d_in[8];
    const float* xyz_w    = (const float*)d_in[9];
    const float* xyz_b    = (const float*)d_in[10];
    const float* wpqr_w   = (const float*)d_in[11];
    const float* wpqr_b   = (const float*)d_in[12];
    float* out = (float*)d_out;

    char* ws = (char*)d_ws;
    float*          partial = (float*)(ws + OFF_PARTIAL);
    unsigned*       xpad    = (unsigned*)(ws + OFF_XPAD);
    unsigned short* wb2     = (unsigned short*)(ws + OFF_WB);
    unsigned short* A2      = (unsigned short*)(ws + OFF_A);
    unsigned short* B2      = (unsigned short*)(ws + OFF_B);

    int img_work = 8 * 3 * 262 * XROW;                 // 830,016
    prep_kernel<<<(img_work + 255) / 256, 256, 0, stream>>>(
        x, conv1_w, bn_gamma, bn_var, xpad, wb2);
    conv_kernel<<<1024, 512, 0, stream>>>(xpad, wb2, bn_gamma, bn_beta,
                                          bn_mean, bn_var, A2, B2);
    pool_kernel<<<1024, 256, 0, stream>>>(A2, B2, partial);
    head_kernel<<<64, 256, 0, stream>>>(ei, partial, fc_w, fc_b,
                                        xyz_w, xyz_b, wpqr_w, wpqr_b, out);
}

// Round 10
// 129.538 us; speedup vs baseline: 2.8705x; 1.0444x over previous
//
#include <hip/hip_runtime.h>
#include <hip/hip_bf16.h>

// Problem constants
#define N_NODES 8
#define N_EDGES 64
#define CO 64
#define OH 128
#define OW 128
#define FEAT 1024
#define BN_EPS 1e-5f

// Workspace layout (bytes):
//   partial @ 0        : 16 rt x 36 pairs x 64 c fp32 = 147,456 (pad 151,552)
//   xpad    @ 151552   : 8*3*262*264 bf16 = 3,320,064
//   wb2     @ 3471616  : 24*128*8 bf16 = 49,152
//   A2      @ 3520768  : 16,777,216
//   B2      @ 20297984 : 16,777,216
#define OFF_PARTIAL 0
#define OFF_XPAD    151552
#define OFF_WB      3471616
#define OFF_A       3520768
#define OFF_B       20297984

#define RS_W 136        // conv raw row stride in u32 words
#define XROW 132        // xpad row stride in u32 words

typedef short bf16x8 __attribute__((ext_vector_type(8)));
typedef float f32x4  __attribute__((ext_vector_type(4)));

__device__ __forceinline__ unsigned short f2bf(float f) {   // RNE f32->bf16
    unsigned u = __float_as_uint(f);
    u += 0x7fffu + ((u >> 16) & 1u);
    return (unsigned short)(u >> 16);
}
__device__ __forceinline__ float blo(unsigned u) { return __uint_as_float(u << 16); }
__device__ __forceinline__ float bhi(unsigned u) { return __uint_as_float(u & 0xffff0000u); }

// ---------------------------------------------------------------------------
// K0: prep — pad+convert image to bf16 once + weight repack (unchanged R9).
__global__ __launch_bounds__(256) void prep_kernel(
        const float* __restrict__ x, const float* __restrict__ w,
        const float* __restrict__ gamma, const float* __restrict__ var,
        unsigned* __restrict__ xpad, unsigned short* __restrict__ wb2) {
    int idx = blockIdx.x * 256 + threadIdx.x;
    if (idx < 8 * 3 * 262 * XROW) {
        int u   = idx % XROW;
        int r   = idx / XROW;
        int iyp = r % 262;
        int nc  = r / 262;
        int iy  = iyp - 3;
        unsigned val = 0u;
        if ((unsigned)iy < 256u) {
            int c0 = 2 * u - 3;
            const float* row = x + (size_t)nc * 65536 + iy * 256;
            float f0 = ((unsigned)c0 < 256u) ? row[c0] : 0.f;
            float f1 = ((unsigned)(c0 + 1) < 256u) ? row[c0 + 1] : 0.f;
            val = (unsigned)f2bf(f0) | ((unsigned)f2bf(f1) << 16);
        }
        xpad[idx] = val;
    }
    if (idx < 2 * 64 * 192) {
        int tp = idx % 192;
        int c  = (idx / 192) & 63;
        int h  = idx / (192 * 64);
        int rr = tp >> 3, kx = tp & 7;
        float val = 0.f;
        if (rr < 21 && kx < 7) {
            int ci = rr / 7, ky = rr % 7;
            float sc = gamma[c] * rsqrtf(var[c] + BN_EPS);
            val = w[((c * 6 + h * 3 + ci) * 7 + ky) * 7 + kx] * sc;
        }
        wb2[(rr * 128 + h * 64 + c) * 8 + kx] = f2bf(val);
    }
}

// ---------------------------------------------------------------------------
// K1: MFMA conv, OCCUPANCY-FOCUSED restructure: 1024 blocks x 1024 thr
// (16 waves). Wave = (h, px-group wg, ct-half): acc[2][2] = 16 VGPR; live set
// ~55-65 VGPR targets the 64-VGPR class -> 32 waves/CU (2 co-resident
// 1024-thr blocks) vs 16 before. Same total MFMA; per-wave work halved.
__global__ __launch_bounds__(1024, 4) void conv_kernel(
        const unsigned* __restrict__ xpad, const unsigned short* __restrict__ wb2,
        const float* __restrict__ gamma, const float* __restrict__ beta,
        const float* __restrict__ mean,  const float* __restrict__ var,
        unsigned short* __restrict__ A2, unsigned short* __restrict__ B2) {
    int bx  = blockIdx.x;
    int r16 = bx & 7;                  // XCD-pinned row-group (matches pool)
    int idx = bx >> 3;
    int n   = idx >> 4;
    int oy  = (r16 << 4) + (idx & 15);
    int t   = threadIdx.x;

    // one 32.8 KB buffer: rawu [24][136] u32 (13 KB), reused as T [128][128] bf16
    __shared__ __align__(16) char smem[32768];
    unsigned* rawu = (unsigned*)smem;

    // stage: 24 rows x 34 uint4 granules (rows 21-23, granule 33 zeroed)
    const unsigned* src = xpad + (size_t)n * (3 * 262 * XROW);
    if (t < 816) {                      // 24*34, single round
        int g  = t % 34;
        int rr = t / 34;
        uint4 v = make_uint4(0u, 0u, 0u, 0u);
        if (rr < 21 && g < 33) {
            int ci = (rr * 147) >> 10;  // rr/7 for rr<24
            int ky = rr - ci * 7;
            v = *(const uint4*)(src + (ci * 262 + 2 * oy + ky) * XROW + 4 * g);
        }
        *(uint4*)&rawu[rr * RS_W + 4 * g] = v;
    }
    __syncthreads();

    int wv = t >> 6, lane = t & 63;
    int h   = wv & 1;
    int wg  = (wv >> 1) & 3;
    int cth = wv >> 3;                  // ct-half: handles ct = 2*cth + {0,1}
    int quad = lane >> 4, m = lane & 15;

    f32x4 acc[2][2];
#pragma unroll
    for (int ctl = 0; ctl < 2; ++ctl) {
        acc[ctl][0] = (f32x4){0.f, 0.f, 0.f, 0.f};
        acc[ctl][1] = (f32x4){0.f, 0.f, 0.f, 0.f};
    }

    const bf16x8* wbv = (const bf16x8*)wb2;

#pragma unroll 2
    for (int s = 0; s < 6; ++s) {
        int rq = 4 * s + quad;
        bf16x8 afrag[2];                // image: A[m=px][k]
#pragma unroll
        for (int nt = 0; nt < 2; ++nt) {
            int ox = 32 * wg + 16 * nt + m;
            int base = rq * RS_W + ox;
            union { unsigned u[4]; bf16x8 v; } bb;
            bb.u[0] = rawu[base];     bb.u[1] = rawu[base + 1];
            bb.u[2] = rawu[base + 2]; bb.u[3] = rawu[base + 3];
            afrag[nt] = bb.v;
        }
#pragma unroll
        for (int ctl = 0; ctl < 2; ++ctl) {
            int ct = 2 * cth + ctl;
            bf16x8 wfrag = wbv[rq * 128 + h * 64 + 16 * ct + m];  // global, L1-hot
#pragma unroll
            for (int nt = 0; nt < 2; ++nt)
                acc[ctl][nt] = __builtin_amdgcn_mfma_f32_16x16x32_bf16(
                                   afrag[nt], wfrag, acc[ctl][nt], 0, 0, 0);
        }
    }

    float sh[2] = {0.f, 0.f};
    if (h) {
#pragma unroll
        for (int ctl = 0; ctl < 2; ++ctl) {
            int c = 16 * (2 * cth + ctl) + m;
            float sc = gamma[c] * rsqrtf(var[c] + BN_EPS);
            sh[ctl] = beta[c] - mean[c] * sc;
        }
    }

    __syncthreads();                    // smem reuse: T transpose buffer
    unsigned short* T = (unsigned short*)smem;   // [128 chp][128 px], swizzled

#pragma unroll
    for (int ctl = 0; ctl < 2; ++ctl) {
        int chp = h * 64 + 16 * (2 * cth + ctl) + m;
        int sw  = (chp & 7) << 2;       // XOR swizzle key (granule = 4 shorts)
#pragma unroll
        for (int nt = 0; nt < 2; ++nt) {
            int px0 = 32 * wg + 16 * nt + 4 * quad;
            float v0 = acc[ctl][nt][0] + sh[ctl];
            float v1 = acc[ctl][nt][1] + sh[ctl];
            float v2 = acc[ctl][nt][2] + sh[ctl];
            float v3 = acc[ctl][nt][3] + sh[ctl];
            uint2 pk;
            pk.x = (unsigned)f2bf(v0) | ((unsigned)f2bf(v1) << 16);
            pk.y = (unsigned)f2bf(v2) | ((unsigned)f2bf(v3) << 16);
            int gs = ((px0 >> 2) ^ sw);
            *(uint2*)&T[chp * 128 + gs * 4] = pk;
        }
    }
    __syncthreads();

    // coalesced store: 1024 thr -> (ch-row, 16-px slot), 2x uint4 each
    int row = t >> 3, slot = t & 7;     // row = h*64 + ch, slot of 16 px
    int hh = row >> 6, ch = row & 63;
    int swr = (row & 7) << 2;
    unsigned short* dst = (hh ? B2 : A2)
                        + ((size_t)(n * CO + ch) << 14) + (oy << 7) + slot * 16;
#pragma unroll
    for (int i = 0; i < 2; ++i) {
        int g  = slot * 4 + i * 2;      // granule of px slot*16 + i*8
        int gs = g ^ swr;
        *(uint4*)(dst + i * 8) = *(uint4*)&T[row * 128 + gs * 4];
    }
}

// ---------------------------------------------------------------------------
// K2: pool over 36 distinct pairs -> non-atomic partial[rt][pair][c]
// (unchanged R9). Grid 1024 = 64 ch x 16 rt, XCD-swizzled.
__global__ __launch_bounds__(256, 4) void pool_kernel(
        const unsigned short* __restrict__ A2,
        const unsigned short* __restrict__ B2,
        float* __restrict__ partial) {
    int pb  = blockIdx.x;
    int xcd = pb & 7;
    int q   = pb >> 3;
    int c   = q >> 1;
    int rt  = xcd * 2 + (q & 1);
    int t   = threadIdx.x;

    __shared__ unsigned short S[2 * 8 * 9 * 128];   // plane 1152, row 128

    for (int k = t; k < 2304; k += 256) {
        int slot = k & 15;
        int r    = (k >> 4) % 9;
        int tn   = (k >> 4) / 9;
        int grow = 8 * rt - 1 + r;
        uint4 v = make_uint4(0u, 0u, 0u, 0u);
        if (grow >= 0) {
            const unsigned short* src = (tn >= 8) ? B2 : A2;
            int node = tn & 7;
            v = *(const uint4*)(src + ((size_t)(node * CO + c) << 14)
                                    + (grow << 7) + slot * 8);
        }
        *(uint4*)&S[tn * 1152 + (r << 7) + slot * 8] = v;
    }
    __syncthreads();

    int wv = t >> 6, lane = t & 63;
    int esub = lane >> 4, tc = lane & 15;

    for (int i = 0; i < 3; ++i) {
        int sidx = 12 * wv + 4 * i + esub;          // pair slot 0..47
        bool valid = sidx < 36;
        int ss = valid ? sidx : 0;
        int pi = 0, rem = ss;                        // unrank (pi<=pj)
        while (rem >= 8 - pi) { rem -= 8 - pi; ++pi; }
        int pj = pi + rem;
        const unsigned short* pa  = &S[pi * 1152];
        const unsigned short* pb2 = &S[(8 + pj) * 1152];

        float mx[4][4];
#pragma unroll
        for (int p = 0; p < 4; ++p)
#pragma unroll
            for (int qq = 0; qq < 4; ++qq) mx[p][qq] = 0.f;

#pragma unroll
        for (int r = 0; r < 9; ++r) {
            uint4 ga = *(const uint4*)(pa + (r << 7) + tc * 8);
            uint4 gb = *(const uint4*)(pb2 + (r << 7) + tc * 8);
            float ha = 0.f, hb = 0.f;
            if (tc > 0) {
                ha = bhi(*(const unsigned*)(pa + (r << 7) + tc * 8 - 2));
                hb = bhi(*(const unsigned*)(pb2 + (r << 7) + tc * 8 - 2));
            }
            float z0 = ha + hb;
            float z1 = blo(ga.x) + blo(gb.x), z2 = bhi(ga.x) + bhi(gb.x);
            float z3 = blo(ga.y) + blo(gb.y), z4 = bhi(ga.y) + bhi(gb.y);
            float z5 = blo(ga.z) + blo(gb.z), z6 = bhi(ga.z) + bhi(gb.z);
            float z7 = blo(ga.w) + blo(gb.w), z8 = bhi(ga.w) + bhi(gb.w);
            float h0 = fmaxf(fmaxf(z0, z1), z2);
            float h1 = fmaxf(fmaxf(z2, z3), z4);
            float h2 = fmaxf(fmaxf(z4, z5), z6);
            float h3 = fmaxf(fmaxf(z6, z7), z8);
            if (r & 1) {
                int p = (r - 1) >> 1;
                mx[p][0] = fmaxf(mx[p][0], h0); mx[p][1] = fmaxf(mx[p][1], h1);
                mx[p][2] = fmaxf(mx[p][2], h2); mx[p][3] = fmaxf(mx[p][3], h3);
            } else {
                if (r >= 2) {
                    int p = (r >> 1) - 1;
                    mx[p][0] = fmaxf(mx[p][0], h0); mx[p][1] = fmaxf(mx[p][1], h1);
                    mx[p][2] = fmaxf(mx[p][2], h2); mx[p][3] = fmaxf(mx[p][3], h3);
                }
                if (r <= 6) {
                    int p = r >> 1;
                    mx[p][0] = fmaxf(mx[p][0], h0); mx[p][1] = fmaxf(mx[p][1], h1);
                    mx[p][2] = fmaxf(mx[p][2], h2); mx[p][3] = fmaxf(mx[p][3], h3);
                }
            }
        }

        float sum = 0.f;
#pragma unroll
        for (int p = 0; p < 4; ++p)
#pragma unroll
            for (int qq = 0; qq < 4; ++qq) sum += fmaxf(mx[p][qq], 0.f);

        sum += __shfl_down(sum, 8, 64);
        sum += __shfl_down(sum, 4, 64);
        sum += __shfl_down(sum, 2, 64);
        sum += __shfl_down(sum, 1, 64);
        if (tc == 0 && valid)
            partial[(rt * 36 + sidx) * 64 + c] = sum;
    }
}

// ---------------------------------------------------------------------------
// K3: head (unchanged R9).
__global__ __launch_bounds__(256) void head_kernel(
        const int* __restrict__ ei, const float* __restrict__ partial,
        const float* __restrict__ fc_w,   const float* __restrict__ fc_b,
        const float* __restrict__ xyz_w,  const float* __restrict__ xyz_b,
        const float* __restrict__ wpqr_w, const float* __restrict__ wpqr_b,
        float* __restrict__ out) {
    int e = blockIdx.x;
    int t = threadIdx.x;
    int a0 = ei[e], a1 = ei[N_EDGES + e];
    int pi = min(a0, a1), pj = max(a0, a1);
    int rank = pi * 8 - ((pi * (pi + 1)) >> 1) + pj;
    __shared__ float pl[CO];
    if (t < CO) {
        float s = 0.f;
#pragma unroll
        for (int rt = 0; rt < 16; ++rt)
            s += partial[(rt * 36 + rank) * 64 + t];
        pl[t] = s * (1.f / 4096.f);
    }
    __syncthreads();

    float s[6] = {0.f, 0.f, 0.f, 0.f, 0.f, 0.f};
#pragma unroll
    for (int ff = 0; ff < 4; ++ff) {
        int f = ff * 256 + t;
        const float* wr = fc_w + f * CO;
        float d = fc_b[f];
#pragma unroll
        for (int c = 0; c < CO; ++c) d = fmaf(pl[c], wr[c], d);
        d = fmaxf(d, 0.f);
#pragma unroll
        for (int r = 0; r < 3; ++r) {
            s[r]     = fmaf(d, xyz_w[r * FEAT + f],  s[r]);
            s[3 + r] = fmaf(d, wpqr_w[r * FEAT + f], s[3 + r]);
        }
    }
#pragma unroll
    for (int r = 0; r < 6; ++r)
#pragma unroll
        for (int off = 32; off > 0; off >>= 1)
            s[r] += __shfl_down(s[r], off, 64);

    __shared__ float red[4][6];
    if ((t & 63) == 0) {
#pragma unroll
        for (int r = 0; r < 6; ++r) red[t >> 6][r] = s[r];
    }
    __syncthreads();
    if (t < 6) {
        float v = red[0][t] + red[1][t] + red[2][t] + red[3][t];
        v += (t < 3) ? xyz_b[t] : wpqr_b[t - 3];
        out[48 + e * 6 + t] = v;
        if (e < 8) out[e * 6 + t] = v;
    }
}

// ---------------------------------------------------------------------------
extern "C" void kernel_launch(void* const* d_in, const int* in_sizes, int n_in,
                              void* d_out, int out_size, void* d_ws, size_t ws_size,
                              hipStream_t stream) {
    const float* x        = (const float*)d_in[0];
    const int*   ei       = (const int*)d_in[1];
    const float* conv1_w  = (const float*)d_in[2];
    const float* bn_gamma = (const float*)d_in[3];
    const float* bn_beta  = (const float*)d_in[4];
    const float* bn_mean  = (const float*)d_in[5];
    const float* bn_var   = (const float*)d_in[6];
    const float* fc_w     = (const float*)d_in[7];
    const float* fc_b     = (const float*)d_in[8];
    const float* xyz_w    = (const float*)d_in[9];
    const float* xyz_b    = (const float*)d_in[10];
    const float* wpqr_w   = (const float*)d_in[11];
    const float* wpqr_b   = (const float*)d_in[12];
    float* out = (float*)d_out;

    char* ws = (char*)d_ws;
    float*          partial = (float*)(ws + OFF_PARTIAL);
    unsigned*       xpad    = (unsigned*)(ws + OFF_XPAD);
    unsigned short* wb2     = (unsigned short*)(ws + OFF_WB);
    unsigned short* A2      = (unsigned short*)(ws + OFF_A);
    unsigned short* B2      = (unsigned short*)(ws + OFF_B);

    int img_work = 8 * 3 * 262 * XROW;
    prep_kernel<<<(img_work + 255) / 256, 256, 0, stream>>>(
        x, conv1_w, bn_gamma, bn_var, xpad, wb2);
    conv_kernel<<<1024, 1024, 0, stream>>>(xpad, wb2, bn_gamma, bn_beta,
                                           bn_mean, bn_var, A2, B2);
    pool_kernel<<<1024, 256, 0, stream>>>(A2, B2, partial);
    head_kernel<<<64, 256, 0, stream>>>(ei, partial, fc_w, fc_b,
                                        xyz_w, xyz_b, wpqr_w, wpqr_b, out);
}